// Round 7
// baseline (808.937 us; speedup 1.0000x reference)
//
#include <hip/hip_runtime.h>
#include <hip/hip_bf16.h>
#include <cstdint>

typedef __bf16 bf16_t;
typedef bf16_t bf16x8 __attribute__((ext_vector_type(8)));
typedef float f32x4 __attribute__((ext_vector_type(4)));

#define MFMA16(a, b, c) __builtin_amdgcn_mfma_f32_16x16x32_bf16(a, b, c, 0, 0, 0)

constexpr int LDK = 72;  // 64 + 8 pad

__global__ void zero_out(unsigned short* __restrict__ out, long n) {
    long i = (long)blockIdx.x * 256 + threadIdx.x;
    if (i < n) out[i] = 0;
}

// Detect input dtype: bf16 (flag=1) or fp32 (flag=0). For bf16 N(0,1) data,
// word bits[14:7] = a bf16 exponent (~112..134): ~all hits; for fp32 they are
// mantissa noise: ~19% hits.
__global__ void detect_dtype(const unsigned* __restrict__ x,
                             int* __restrict__ flag) {
    if (threadIdx.x == 0 && blockIdx.x == 0) {
        int cnt = 0;
        for (int i = 0; i < 1024; ++i) {
            unsigned e = (x[i] >> 7) & 0xFF;
            cnt += (e > 100 && e < 150) ? 1 : 0;
        }
        *flag = (cnt > 512) ? 1 : 0;
    }
}

__global__ void transpose_flex(const void* __restrict__ in,
                               bf16_t* __restrict__ out, int R, int C,
                               const int* __restrict__ flagp) {
    const int fl = *flagp;
    __shared__ bf16_t tile[32][33];
    int c0 = blockIdx.x * 32, r0 = blockIdx.y * 32;
    int x = threadIdx.x, y = threadIdx.y;  // 32 x 8
#pragma unroll
    for (int i = 0; i < 4; ++i) {
        long idx = (long)(r0 + y + 8 * i) * C + c0 + x;
        bf16_t v = fl ? ((const bf16_t*)in)[idx]
                      : (bf16_t)((const float*)in)[idx];
        tile[y + 8 * i][x] = v;
    }
    __syncthreads();
#pragma unroll
    for (int i = 0; i < 4; ++i)
        out[(long)(c0 + y + 8 * i) * R + r0 + x] = tile[x][y + 8 * i];
}

// C[(c_row0+m)][n] = sum_k A[(a_row0+m)][k] * Bt[n][k]  (+ bias[n])
// AFLEX: A dtype per flag. OUTFLEX: C dtype per flag (fp32 if flag=0).
template <bool AFLEX, bool BIAS, bool OUTFLEX>
__global__ __launch_bounds__(256) void gemm128(
    const void* __restrict__ A, const bf16_t* __restrict__ Bt, int K, int lda,
    long a_row0, void* __restrict__ C, int ldc, long c_row0,
    const void* __restrict__ bias, const int* __restrict__ flagp) {
    const int fl = *flagp;
    __shared__ bf16_t a_lds[128 * LDK];
    __shared__ bf16_t b_lds[128 * LDK];
    int t = threadIdx.x;
    int wave = t >> 6, lane = t & 63;
    int m16 = lane & 15, quad = lane >> 4;
    int wr = wave >> 1, wc = wave & 1;
    long m0 = (long)blockIdx.y * 128;
    int n0 = blockIdx.x * 128;

    f32x4 acc[4][4] = {};

    for (int ks = 0; ks < K; ks += 64) {
#pragma unroll
        for (int i = 0; i < 4; ++i) {
            int c = t + 256 * i;
            int row = c >> 3;
            int kc = (c & 7) << 3;
            bf16x8 av;
            if (AFLEX && !fl) {
                const float* Af = (const float*)A;
                long base = (a_row0 + m0 + row) * (long)lda + ks + kc;
#pragma unroll
                for (int e = 0; e < 8; ++e) av[e] = (bf16_t)Af[base + e];
            } else {
                av = *(const bf16x8*)&(
                    (const bf16_t*)A)[(a_row0 + m0 + row) * (long)lda + ks + kc];
            }
            *(bf16x8*)&a_lds[row * LDK + kc] = av;
            *(bf16x8*)&b_lds[row * LDK + kc] =
                *(const bf16x8*)&Bt[(long)(n0 + row) * K + ks + kc];
        }
        __syncthreads();
#pragma unroll
        for (int kf = 0; kf < 2; ++kf) {
            bf16x8 af[4], bfr[4];
#pragma unroll
            for (int mb = 0; mb < 4; ++mb)
                af[mb] = *(const bf16x8*)&a_lds[(wr * 64 + mb * 16 + m16) * LDK +
                                                kf * 32 + quad * 8];
#pragma unroll
            for (int nb = 0; nb < 4; ++nb)
                bfr[nb] = *(const bf16x8*)&b_lds[(wc * 64 + nb * 16 + m16) * LDK +
                                                 kf * 32 + quad * 8];
#pragma unroll
            for (int mb = 0; mb < 4; ++mb)
#pragma unroll
                for (int nb = 0; nb < 4; ++nb)
                    acc[mb][nb] = MFMA16(af[mb], bfr[nb], acc[mb][nb]);
        }
        __syncthreads();
    }

#pragma unroll
    for (int mb = 0; mb < 4; ++mb) {
#pragma unroll
        for (int nb = 0; nb < 4; ++nb) {
            int col = n0 + wc * 64 + nb * 16 + m16;
#pragma unroll
            for (int r = 0; r < 4; ++r) {
                long row = m0 + wr * 64 + mb * 16 + quad * 4 + r;
                float v = acc[mb][nb][r];
                if (BIAS) {
                    float bb = fl ? (float)((const bf16_t*)bias)[col]
                                  : ((const float*)bias)[col];
                    v += bb;
                }
                long off = (c_row0 + row) * (long)ldc + col;
                if (OUTFLEX && !fl)
                    ((float*)C)[off] = v;
                else
                    ((bf16_t*)C)[off] = (bf16_t)v;
            }
        }
    }
}

// Flash attention over packed qkv [chunk*1024, 1536] (bf16, ours).
// att written in-place into the Q columns. 1 WG = (qt, h, b).
__global__ __launch_bounds__(256) void flash_attn(
    bf16_t* __restrict__ qkv, const int* __restrict__ rel_index,
    const void* __restrict__ bias_table, const int* __restrict__ flagp) {
    const int fl = *flagp;
    __shared__ bf16_t k_lds[64 * LDK];
    __shared__ bf16_t vt_lds[64 * LDK];
    __shared__ bf16_t p_lds[4 * 16 * LDK];

    int t = threadIdx.x;
    int wave = t >> 6, lane = t & 63;
    int m16 = lane & 15, quad = lane >> 4;
    int qt = blockIdx.x;
    int h = blockIdx.y;
    int b = blockIdx.z;
    int qrow0 = qt * 64 + wave * 16;
    bf16_t* base = qkv + (long)b * 1024 * 1536;
    bf16_t* qb = base + h * 64;
    const bf16_t* kb = base + 512 + h * 64;
    const bf16_t* vb = base + 1024 + h * 64;

    bf16x8 qa0 = *(const bf16x8*)&qb[(qrow0 + m16) * 1536 + quad * 8];
    bf16x8 qa1 = *(const bf16x8*)&qb[(qrow0 + m16) * 1536 + 32 + quad * 8];

    float mrun[4], lrun[4];
    f32x4 oacc[4] = {};
#pragma unroll
    for (int r = 0; r < 4; ++r) { mrun[r] = -1e30f; lrun[r] = 0.f; }

    int qi[4];
#pragma unroll
    for (int r = 0; r < 4; ++r) qi[r] = qt * 64 + wave * 16 + quad * 4 + r;

    const float SCALE = 0.125f;

    for (int j0 = 0; j0 < 1024; j0 += 64) {
#pragma unroll
        for (int i = 0; i < 2; ++i) {
            int cc = t + 256 * i;
            int row = cc >> 3, dc = (cc & 7) << 3;
            *(bf16x8*)&k_lds[row * LDK + dc] =
                *(const bf16x8*)&kb[(long)(j0 + row) * 1536 + dc];
        }
#pragma unroll
        for (int i = 0; i < 2; ++i) {
            int j = t & 63;
            int dc = ((t >> 6) + 4 * i) * 8;
            bf16x8 vv = *(const bf16x8*)&vb[(long)(j0 + j) * 1536 + dc];
#pragma unroll
            for (int e = 0; e < 8; ++e) vt_lds[(dc + e) * LDK + j] = vv[e];
        }
        __syncthreads();

        f32x4 s[4];
#pragma unroll
        for (int cb = 0; cb < 4; ++cb) {
            bf16x8 kf0 = *(const bf16x8*)&k_lds[(cb * 16 + m16) * LDK + quad * 8];
            bf16x8 kf1 =
                *(const bf16x8*)&k_lds[(cb * 16 + m16) * LDK + 32 + quad * 8];
            f32x4 z = {};
            z = MFMA16(qa0, kf0, z);
            z = MFMA16(qa1, kf1, z);
            s[cb] = z;
        }

        float sv[4][4];
#pragma unroll
        for (int cb = 0; cb < 4; ++cb) {
            int kj = j0 + cb * 16 + m16;
#pragma unroll
            for (int r = 0; r < 4; ++r) {
                int ridx = rel_index[(long)qi[r] * 1024 + kj];
                ridx = ridx < 0 ? 0 : (ridx > 44 ? 44 : ridx);
                float bias = fl ? (float)((const bf16_t*)bias_table)[ridx * 8 + h]
                                : ((const float*)bias_table)[ridx * 8 + h];
                sv[cb][r] = fmaf(s[cb][r], SCALE, bias);
            }
        }

        float mnew[4], alpha[4];
#pragma unroll
        for (int r = 0; r < 4; ++r) {
            float mx = fmaxf(fmaxf(sv[0][r], sv[1][r]), fmaxf(sv[2][r], sv[3][r]));
            mx = fmaxf(mx, __shfl_xor(mx, 1));
            mx = fmaxf(mx, __shfl_xor(mx, 2));
            mx = fmaxf(mx, __shfl_xor(mx, 4));
            mx = fmaxf(mx, __shfl_xor(mx, 8));
            mnew[r] = fmaxf(mrun[r], mx);
            alpha[r] = __expf(mrun[r] - mnew[r]);
            mrun[r] = mnew[r];
        }
        float p[4][4], rs[4] = {0.f, 0.f, 0.f, 0.f};
#pragma unroll
        for (int cb = 0; cb < 4; ++cb)
#pragma unroll
            for (int r = 0; r < 4; ++r) {
                float pp = __expf(sv[cb][r] - mnew[r]);
                p[cb][r] = pp;
                rs[r] += pp;
            }
#pragma unroll
        for (int r = 0; r < 4; ++r) {
            float s4 = rs[r];
            s4 += __shfl_xor(s4, 1);
            s4 += __shfl_xor(s4, 2);
            s4 += __shfl_xor(s4, 4);
            s4 += __shfl_xor(s4, 8);
            lrun[r] = lrun[r] * alpha[r] + s4;
        }
#pragma unroll
        for (int db = 0; db < 4; ++db)
#pragma unroll
            for (int r = 0; r < 4; ++r) oacc[db][r] *= alpha[r];

        bf16_t* pw = &p_lds[wave * 16 * LDK];
#pragma unroll
        for (int cb = 0; cb < 4; ++cb)
#pragma unroll
            for (int r = 0; r < 4; ++r)
                pw[(quad * 4 + r) * LDK + cb * 16 + m16] = (bf16_t)p[cb][r];
        __syncthreads();

        bf16x8 pa0 = *(const bf16x8*)&pw[m16 * LDK + quad * 8];
        bf16x8 pa1 = *(const bf16x8*)&pw[m16 * LDK + 32 + quad * 8];
#pragma unroll
        for (int db = 0; db < 4; ++db) {
            bf16x8 vf0 =
                *(const bf16x8*)&vt_lds[(db * 16 + m16) * LDK + quad * 8];
            bf16x8 vf1 =
                *(const bf16x8*)&vt_lds[(db * 16 + m16) * LDK + 32 + quad * 8];
            oacc[db] = MFMA16(pa0, vf0, oacc[db]);
            oacc[db] = MFMA16(pa1, vf1, oacc[db]);
        }
        __syncthreads();
    }

#pragma unroll
    for (int db = 0; db < 4; ++db)
#pragma unroll
        for (int r = 0; r < 4; ++r) {
            float o = oacc[db][r] / lrun[r];
            int n = qrow0 + quad * 4 + r;
            qb[(long)n * 1536 + db * 16 + m16] = (bf16_t)o;
        }
}

extern "C" void kernel_launch(void* const* d_in, const int* in_sizes, int n_in,
                              void* d_out, int out_size, void* d_ws,
                              size_t ws_size, hipStream_t stream) {
    // Identify inputs by flat element count (all distinct) — order-robust.
    const void* x = nullptr;
    const void* w_qkv = nullptr;
    const void* bias_table = nullptr;
    const void* w_out = nullptr;
    const void* b_out = nullptr;
    const void* rel_raw = nullptr;
    for (int i = 0; i < n_in; ++i) {
        switch (in_sizes[i]) {
            case 16777216: x = d_in[i]; break;
            case 786432:  w_qkv = d_in[i]; break;
            case 360:     bias_table = d_in[i]; break;
            case 262144:  w_out = d_in[i]; break;
            case 512:     b_out = d_in[i]; break;
            case 1048576: rel_raw = d_in[i]; break;
            default: break;
        }
    }
    if (!x || !w_qkv || !bias_table || !w_out || !b_out || !rel_raw) {
        x = d_in[0]; w_qkv = d_in[1]; bias_table = d_in[2];
        w_out = d_in[3]; b_out = d_in[4]; rel_raw = d_in[5];
    }
    const int* rel_index = (const int*)rel_raw;

    char* ws = (char*)d_ws;
    bf16_t* wqkvT = (bf16_t*)ws;
    bf16_t* woutT = (bf16_t*)(ws + 1572864);
    int* flag = (int*)(ws + 1572864 + 524288);
    const size_t fixed = 1572864 + 524288 + 256;
    bf16_t* qkv = (bf16_t*)(ws + fixed);
    const size_t per_batch = (size_t)1024 * 1536 * sizeof(bf16_t);

    if (ws_size < fixed + per_batch) {
        long n = (long)out_size;
        long nblk = (n + 255) / 256;
        if (nblk > 0)
            zero_out<<<(unsigned)nblk, 256, 0, stream>>>(
                (unsigned short*)d_out, n);
        return;
    }

    size_t avail = ws_size - fixed;
    int chunk = (int)(avail / per_batch);
    if (chunk > 32) chunk = 32;
    if (chunk < 1) chunk = 1;
    while (32 % chunk) --chunk;

    detect_dtype<<<1, 64, 0, stream>>>((const unsigned*)x, flag);
    transpose_flex<<<dim3(1536 / 32, 512 / 32), dim3(32, 8), 0, stream>>>(
        w_qkv, wqkvT, 512, 1536, flag);
    transpose_flex<<<dim3(512 / 32, 512 / 32), dim3(32, 8), 0, stream>>>(
        w_out, woutT, 512, 512, flag);

    for (int b0 = 0; b0 < 32; b0 += chunk) {
        long row0 = (long)b0 * 1024;
        int mrows = chunk * 1024;
        gemm128<true, false, false>
            <<<dim3(1536 / 128, mrows / 128), 256, 0, stream>>>(
                x, wqkvT, 512, 512, row0, qkv, 1536, 0, nullptr, flag);
        flash_attn<<<dim3(16, 8, chunk), 256, 0, stream>>>(qkv, rel_index,
                                                           bias_table, flag);
        gemm128<false, true, true>
            <<<dim3(512 / 128, mrows / 128), 256, 0, stream>>>(
                qkv, woutT, 512, 1536, 0, d_out, 512, row0, b_out, flag);
    }
}

// Round 8
// 636.683 us; speedup vs baseline: 1.2705x; 1.2705x over previous
//
#include <hip/hip_runtime.h>
#include <hip/hip_bf16.h>
#include <cstdint>

typedef __bf16 bf16_t;
typedef bf16_t bf16x8 __attribute__((ext_vector_type(8)));
typedef float f32x4 __attribute__((ext_vector_type(4)));

#define MFMA16(a, b, c) __builtin_amdgcn_mfma_f32_16x16x32_bf16(a, b, c, 0, 0, 0)

constexpr int LDK = 72;  // 64 + 8 pad

__global__ void zero_out(unsigned short* __restrict__ out, long n) {
    long i = (long)blockIdx.x * 256 + threadIdx.x;
    if (i < n) out[i] = 0;
}

// Detect input dtype: bf16 (flag=1) or fp32 (flag=0).  (fp32 confirmed on
// this harness in R7, but keep the flex machinery — it's cheap and safe.)
__global__ void detect_dtype(const unsigned* __restrict__ x,
                             int* __restrict__ flag) {
    if (threadIdx.x == 0 && blockIdx.x == 0) {
        int cnt = 0;
        for (int i = 0; i < 1024; ++i) {
            unsigned e = (x[i] >> 7) & 0xFF;
            cnt += (e > 100 && e < 150) ? 1 : 0;
        }
        *flag = (cnt > 512) ? 1 : 0;
    }
}

__global__ void transpose_flex(const void* __restrict__ in,
                               bf16_t* __restrict__ out, int R, int C,
                               const int* __restrict__ flagp) {
    const int fl = *flagp;
    __shared__ bf16_t tile[32][33];
    int c0 = blockIdx.x * 32, r0 = blockIdx.y * 32;
    int x = threadIdx.x, y = threadIdx.y;  // 32 x 8
#pragma unroll
    for (int i = 0; i < 4; ++i) {
        long idx = (long)(r0 + y + 8 * i) * C + c0 + x;
        bf16_t v = fl ? ((const bf16_t*)in)[idx]
                      : (bf16_t)((const float*)in)[idx];
        tile[y + 8 * i][x] = v;
    }
    __syncthreads();
#pragma unroll
    for (int i = 0; i < 4; ++i)
        out[(long)(c0 + y + 8 * i) * R + r0 + x] = tile[x][y + 8 * i];
}

// ---------------------------------------------------------------------------
// Dense relative-bias precompute: rel_bias[h][i*1024+j] (bf16, 16 MB).
// Removes flash's 2-level dependent gather (rel_index -> bias_table).
// ---------------------------------------------------------------------------
__global__ __launch_bounds__(256) void build_bias(
    const int* __restrict__ rel_index, const void* __restrict__ bias_table,
    bf16_t* __restrict__ rel_bias, const int* __restrict__ flagp) {
    const int fl = *flagp;
    long ij = (long)blockIdx.x * 256 + threadIdx.x;  // 0..2^20-1
    int ridx = rel_index[ij];
    ridx = ridx < 0 ? 0 : (ridx > 44 ? 44 : ridx);
#pragma unroll
    for (int h = 0; h < 8; ++h) {
        float b = fl ? (float)((const bf16_t*)bias_table)[ridx * 8 + h]
                     : ((const float*)bias_table)[ridx * 8 + h];
        rel_bias[(long)h * 1048576 + ij] = (bf16_t)b;
    }
}

// C[(c_row0+m)][n] = sum_k A[(a_row0+m)][k] * Bt[n][k]  (+ bias[n])
// AFLEX: A dtype per flag. OUTFLEX: C dtype per flag (fp32 if flag=0).
template <bool AFLEX, bool BIAS, bool OUTFLEX>
__global__ __launch_bounds__(256) void gemm128(
    const void* __restrict__ A, const bf16_t* __restrict__ Bt, int K, int lda,
    long a_row0, void* __restrict__ C, int ldc, long c_row0,
    const void* __restrict__ bias, const int* __restrict__ flagp) {
    const int fl = *flagp;
    __shared__ bf16_t a_lds[128 * LDK];
    __shared__ bf16_t b_lds[128 * LDK];
    int t = threadIdx.x;
    int wave = t >> 6, lane = t & 63;
    int m16 = lane & 15, quad = lane >> 4;
    int wr = wave >> 1, wc = wave & 1;
    long m0 = (long)blockIdx.y * 128;
    int n0 = blockIdx.x * 128;

    f32x4 acc[4][4] = {};

    for (int ks = 0; ks < K; ks += 64) {
#pragma unroll
        for (int i = 0; i < 4; ++i) {
            int c = t + 256 * i;
            int row = c >> 3;
            int kc = (c & 7) << 3;
            bf16x8 av;
            if (AFLEX && !fl) {
                const float* Af = (const float*)A;
                long base = (a_row0 + m0 + row) * (long)lda + ks + kc;
                f32x4 lo = *(const f32x4*)&Af[base];
                f32x4 hi = *(const f32x4*)&Af[base + 4];
#pragma unroll
                for (int e = 0; e < 4; ++e) {
                    av[e] = (bf16_t)lo[e];
                    av[e + 4] = (bf16_t)hi[e];
                }
            } else {
                av = *(const bf16x8*)&(
                    (const bf16_t*)A)[(a_row0 + m0 + row) * (long)lda + ks + kc];
            }
            *(bf16x8*)&a_lds[row * LDK + kc] = av;
            *(bf16x8*)&b_lds[row * LDK + kc] =
                *(const bf16x8*)&Bt[(long)(n0 + row) * K + ks + kc];
        }
        __syncthreads();
#pragma unroll
        for (int kf = 0; kf < 2; ++kf) {
            bf16x8 af[4], bfr[4];
#pragma unroll
            for (int mb = 0; mb < 4; ++mb)
                af[mb] = *(const bf16x8*)&a_lds[(wr * 64 + mb * 16 + m16) * LDK +
                                                kf * 32 + quad * 8];
#pragma unroll
            for (int nb = 0; nb < 4; ++nb)
                bfr[nb] = *(const bf16x8*)&b_lds[(wc * 64 + nb * 16 + m16) * LDK +
                                                 kf * 32 + quad * 8];
#pragma unroll
            for (int mb = 0; mb < 4; ++mb)
#pragma unroll
                for (int nb = 0; nb < 4; ++nb)
                    acc[mb][nb] = MFMA16(af[mb], bfr[nb], acc[mb][nb]);
        }
        __syncthreads();
    }

#pragma unroll
    for (int mb = 0; mb < 4; ++mb) {
#pragma unroll
        for (int nb = 0; nb < 4; ++nb) {
            int col = n0 + wc * 64 + nb * 16 + m16;
#pragma unroll
            for (int r = 0; r < 4; ++r) {
                long row = m0 + wr * 64 + mb * 16 + quad * 4 + r;
                float v = acc[mb][nb][r];
                if (BIAS) {
                    float bb = fl ? (float)((const bf16_t*)bias)[col]
                                  : ((const float*)bias)[col];
                    v += bb;
                }
                long off = (c_row0 + row) * (long)ldc + col;
                if (OUTFLEX && !fl)
                    ((float*)C)[off] = v;
                else
                    ((bf16_t*)C)[off] = (bf16_t)v;
            }
        }
    }
}

// ---------------------------------------------------------------------------
// Flash attention over packed qkv [chunk*1024, 1536] (bf16, ours).
// Bias now read from dense rel_bias[h][i][j] via LDS staging (coalesced).
// att written in-place into the Q columns. 1 WG = (qt, h, b).
// ---------------------------------------------------------------------------
__global__ __launch_bounds__(256) void flash_attn(
    bf16_t* __restrict__ qkv, const bf16_t* __restrict__ rel_bias) {
    __shared__ bf16_t k_lds[64 * LDK];
    __shared__ bf16_t vt_lds[64 * LDK];
    __shared__ bf16_t p_lds[4 * 16 * LDK];
    __shared__ bf16_t sb_lds[64 * 68];  // bias tile [qrow_local][j_local]

    int t = threadIdx.x;
    int wave = t >> 6, lane = t & 63;
    int m16 = lane & 15, quad = lane >> 4;
    int qt = blockIdx.x;
    int h = blockIdx.y;
    int b = blockIdx.z;
    int qrow0 = qt * 64 + wave * 16;
    bf16_t* base = qkv + (long)b * 1024 * 1536;
    bf16_t* qb = base + h * 64;
    const bf16_t* kb = base + 512 + h * 64;
    const bf16_t* vb = base + 1024 + h * 64;
    const bf16_t* rbh = rel_bias + (long)h * 1048576 + (long)(qt * 64) * 1024;

    bf16x8 qa0 = *(const bf16x8*)&qb[(qrow0 + m16) * 1536 + quad * 8];
    bf16x8 qa1 = *(const bf16x8*)&qb[(qrow0 + m16) * 1536 + 32 + quad * 8];

    float mrun[4], lrun[4];
    f32x4 oacc[4] = {};
#pragma unroll
    for (int r = 0; r < 4; ++r) { mrun[r] = -1e30f; lrun[r] = 0.f; }

    const float SCALE = 0.125f;

    for (int j0 = 0; j0 < 1024; j0 += 64) {
        // ---- stage K tile [j][d] ----
#pragma unroll
        for (int i = 0; i < 2; ++i) {
            int cc = t + 256 * i;
            int row = cc >> 3, dc = (cc & 7) << 3;
            *(bf16x8*)&k_lds[row * LDK + dc] =
                *(const bf16x8*)&kb[(long)(j0 + row) * 1536 + dc];
        }
        // ---- stage V^T tile [d][j] ----
#pragma unroll
        for (int i = 0; i < 2; ++i) {
            int j = t & 63;
            int dc = ((t >> 6) + 4 * i) * 8;
            bf16x8 vv = *(const bf16x8*)&vb[(long)(j0 + j) * 1536 + dc];
#pragma unroll
            for (int e = 0; e < 8; ++e) vt_lds[(dc + e) * LDK + j] = vv[e];
        }
        // ---- stage bias tile [qrow_local][j_local] (coalesced bf16x8) ----
#pragma unroll
        for (int i = 0; i < 2; ++i) {
            int idx = t + 256 * i;          // 0..511
            int row = idx >> 3;             // 0..63
            int jc = (idx & 7) << 3;        // 0..56
            *(bf16x8*)&sb_lds[row * 68 + jc] =
                *(const bf16x8*)&rbh[(long)row * 1024 + j0 + jc];
        }
        __syncthreads();

        // ---- S = Q K^T ----
        f32x4 s[4];
#pragma unroll
        for (int cb = 0; cb < 4; ++cb) {
            bf16x8 kf0 = *(const bf16x8*)&k_lds[(cb * 16 + m16) * LDK + quad * 8];
            bf16x8 kf1 =
                *(const bf16x8*)&k_lds[(cb * 16 + m16) * LDK + 32 + quad * 8];
            f32x4 z = {};
            z = MFMA16(qa0, kf0, z);
            z = MFMA16(qa1, kf1, z);
            s[cb] = z;
        }

        // ---- scale + bias (from LDS; 2-way pattern, conflict-free) ----
        float sv[4][4];
#pragma unroll
        for (int cb = 0; cb < 4; ++cb)
#pragma unroll
            for (int r = 0; r < 4; ++r) {
                float bias = (float)
                    sb_lds[(wave * 16 + quad * 4 + r) * 68 + cb * 16 + m16];
                sv[cb][r] = fmaf(s[cb][r], SCALE, bias);
            }

        // ---- online softmax ----
        float mnew[4], alpha[4];
#pragma unroll
        for (int r = 0; r < 4; ++r) {
            float mx = fmaxf(fmaxf(sv[0][r], sv[1][r]), fmaxf(sv[2][r], sv[3][r]));
            mx = fmaxf(mx, __shfl_xor(mx, 1));
            mx = fmaxf(mx, __shfl_xor(mx, 2));
            mx = fmaxf(mx, __shfl_xor(mx, 4));
            mx = fmaxf(mx, __shfl_xor(mx, 8));
            mnew[r] = fmaxf(mrun[r], mx);
            alpha[r] = __expf(mrun[r] - mnew[r]);
            mrun[r] = mnew[r];
        }
        float p[4][4], rs[4] = {0.f, 0.f, 0.f, 0.f};
#pragma unroll
        for (int cb = 0; cb < 4; ++cb)
#pragma unroll
            for (int r = 0; r < 4; ++r) {
                float pp = __expf(sv[cb][r] - mnew[r]);
                p[cb][r] = pp;
                rs[r] += pp;
            }
#pragma unroll
        for (int r = 0; r < 4; ++r) {
            float s4 = rs[r];
            s4 += __shfl_xor(s4, 1);
            s4 += __shfl_xor(s4, 2);
            s4 += __shfl_xor(s4, 4);
            s4 += __shfl_xor(s4, 8);
            lrun[r] = lrun[r] * alpha[r] + s4;
        }
#pragma unroll
        for (int db = 0; db < 4; ++db)
#pragma unroll
            for (int r = 0; r < 4; ++r) oacc[db][r] *= alpha[r];

        // ---- P: C-layout -> LDS -> A-layout ----
        bf16_t* pw = &p_lds[wave * 16 * LDK];
#pragma unroll
        for (int cb = 0; cb < 4; ++cb)
#pragma unroll
            for (int r = 0; r < 4; ++r)
                pw[(quad * 4 + r) * LDK + cb * 16 + m16] = (bf16_t)p[cb][r];
        __syncthreads();

        // ---- O += P V ----
        bf16x8 pa0 = *(const bf16x8*)&pw[m16 * LDK + quad * 8];
        bf16x8 pa1 = *(const bf16x8*)&pw[m16 * LDK + 32 + quad * 8];
#pragma unroll
        for (int db = 0; db < 4; ++db) {
            bf16x8 vf0 =
                *(const bf16x8*)&vt_lds[(db * 16 + m16) * LDK + quad * 8];
            bf16x8 vf1 =
                *(const bf16x8*)&vt_lds[(db * 16 + m16) * LDK + 32 + quad * 8];
            oacc[db] = MFMA16(pa0, vf0, oacc[db]);
            oacc[db] = MFMA16(pa1, vf1, oacc[db]);
        }
        __syncthreads();
    }

#pragma unroll
    for (int db = 0; db < 4; ++db)
#pragma unroll
        for (int r = 0; r < 4; ++r) {
            float o = oacc[db][r] / lrun[r];
            int n = qrow0 + quad * 4 + r;
            qb[(long)n * 1536 + db * 16 + m16] = (bf16_t)o;
        }
}

extern "C" void kernel_launch(void* const* d_in, const int* in_sizes, int n_in,
                              void* d_out, int out_size, void* d_ws,
                              size_t ws_size, hipStream_t stream) {
    // Identify inputs by flat element count (all distinct) — order-robust.
    const void* x = nullptr;
    const void* w_qkv = nullptr;
    const void* bias_table = nullptr;
    const void* w_out = nullptr;
    const void* b_out = nullptr;
    const void* rel_raw = nullptr;
    for (int i = 0; i < n_in; ++i) {
        switch (in_sizes[i]) {
            case 16777216: x = d_in[i]; break;
            case 786432:  w_qkv = d_in[i]; break;
            case 360:     bias_table = d_in[i]; break;
            case 262144:  w_out = d_in[i]; break;
            case 512:     b_out = d_in[i]; break;
            case 1048576: rel_raw = d_in[i]; break;
            default: break;
        }
    }
    if (!x || !w_qkv || !bias_table || !w_out || !b_out || !rel_raw) {
        x = d_in[0]; w_qkv = d_in[1]; bias_table = d_in[2];
        w_out = d_in[3]; b_out = d_in[4]; rel_raw = d_in[5];
    }
    const int* rel_index = (const int*)rel_raw;

    char* ws = (char*)d_ws;
    bf16_t* wqkvT = (bf16_t*)ws;                           // 1,572,864 B
    bf16_t* woutT = (bf16_t*)(ws + 1572864);               // 524,288 B
    int* flag = (int*)(ws + 1572864 + 524288);             // 256 B slot
    bf16_t* rel_bias = (bf16_t*)(ws + 1572864 + 524288 + 256);  // 16 MiB
    const size_t fixed = 1572864 + 524288 + 256 + 16777216;
    bf16_t* qkv = (bf16_t*)(ws + fixed);
    const size_t per_batch = (size_t)1024 * 1536 * sizeof(bf16_t);  // 3 MiB

    if (ws_size < fixed + per_batch) {
        long n = (long)out_size;
        long nblk = (n + 255) / 256;
        if (nblk > 0)
            zero_out<<<(unsigned)nblk, 256, 0, stream>>>(
                (unsigned short*)d_out, n);
        return;
    }

    size_t avail = ws_size - fixed;
    int chunk = (int)(avail / per_batch);
    if (chunk > 32) chunk = 32;
    if (chunk < 1) chunk = 1;
    while (32 % chunk) --chunk;

    detect_dtype<<<1, 64, 0, stream>>>((const unsigned*)x, flag);
    transpose_flex<<<dim3(1536 / 32, 512 / 32), dim3(32, 8), 0, stream>>>(
        w_qkv, wqkvT, 512, 1536, flag);
    transpose_flex<<<dim3(512 / 32, 512 / 32), dim3(32, 8), 0, stream>>>(
        w_out, woutT, 512, 512, flag);
    build_bias<<<4096, 256, 0, stream>>>(rel_index, bias_table, rel_bias, flag);

    for (int b0 = 0; b0 < 32; b0 += chunk) {
        long row0 = (long)b0 * 1024;
        int mrows = chunk * 1024;
        gemm128<true, false, false>
            <<<dim3(1536 / 128, mrows / 128), 256, 0, stream>>>(
                x, wqkvT, 512, 512, row0, qkv, 1536, 0, nullptr, flag);
        flash_attn<<<dim3(16, 8, chunk), 256, 0, stream>>>(qkv, rel_bias);
        gemm128<false, true, true>
            <<<dim3(512 / 128, mrows / 128), 256, 0, stream>>>(
                qkv, woutT, 512, 1536, 0, d_out, 512, row0, b_out, flag);
    }
}